// Round 10
// baseline (251.179 us; speedup 1.0000x reference)
//
#include <hip/hip_runtime.h>
#include <hip/hip_bf16.h>

typedef __bf16 bf16x8 __attribute__((ext_vector_type(8)));
typedef float  f32x4  __attribute__((ext_vector_type(4)));
typedef float  f32x16 __attribute__((ext_vector_type(16)));

// async 16B global -> LDS (wave-uniform LDS base + lane*16)
__device__ __forceinline__ void gload_lds16(const void* g, void* l) {
  __builtin_amdgcn_global_load_lds(
      (const __attribute__((address_space(1))) unsigned int*)g,
      (__attribute__((address_space(3))) unsigned int*)l, 16, 0, 0);
}

// ---------------- fp32 -> bf16 convert (vectorized) ----------------
__global__ void k_cvt(const float* __restrict__ s, __bf16* __restrict__ d, int n4) {
  int i = blockIdx.x * blockDim.x + threadIdx.x;
  if (i >= n4) return;
  float4 v = ((const float4*)s)[i];
  union { __bf16 h[4]; uint2 u; } o;
  o.h[0] = (__bf16)v.x; o.h[1] = (__bf16)v.y;
  o.h[2] = (__bf16)v.z; o.h[3] = (__bf16)v.w;
  ((uint2*)d)[i] = o.u;
}

// ---------------- C[M,N] = A[M,K] @ B[N,K]^T + bias ---------------- (proven, verbatim)
template<bool OUT_BF16>
__global__ __launch_bounds__(256, 2)
void k_gemm_bt(const __bf16* __restrict__ A, const __bf16* __restrict__ B,
               const float* __restrict__ bias, void* __restrict__ C,
               int M, int N, int K) {
  __shared__ __align__(16) __bf16 At[128 * 32];
  __shared__ __align__(16) __bf16 Bt[64 * 32];
  const int tid  = threadIdx.x;
  const int lane = tid & 63;
  const int w    = tid >> 6;
  const int wr   = w >> 1, wc = w & 1;
  const int bm   = blockIdx.y * 128, bn = blockIdx.x * 64;

  f32x4 acc[4][2] = {};

  const __bf16* ga = A + (size_t)(bm + (tid >> 2)) * K + (tid & 3) * 8;
  const __bf16* gb = B + (size_t)(bn + (tid >> 2)) * K + (tid & 3) * 8;

  for (int k0 = 0; k0 < K; k0 += 32) {
    __syncthreads();
    gload_lds16(ga + k0,                  &At[(w * 16) * 32]);
    gload_lds16(ga + k0 + (size_t)64 * K, &At[(64 + w * 16) * 32]);
    gload_lds16(gb + k0,                  &Bt[(w * 16) * 32]);
    __syncthreads();

    bf16x8 a[4], b[2];
#pragma unroll
    for (int mt = 0; mt < 4; ++mt)
      a[mt] = *(const bf16x8*)&At[(wr * 64 + mt * 16 + (lane & 15)) * 32 + (lane >> 4) * 8];
#pragma unroll
    for (int nt = 0; nt < 2; ++nt)
      b[nt] = *(const bf16x8*)&Bt[(wc * 32 + nt * 16 + (lane & 15)) * 32 + (lane >> 4) * 8];
    __builtin_amdgcn_s_setprio(1);
#pragma unroll
    for (int mt = 0; mt < 4; ++mt)
#pragma unroll
      for (int nt = 0; nt < 2; ++nt)
        acc[mt][nt] = __builtin_amdgcn_mfma_f32_16x16x32_bf16(a[mt], b[nt], acc[mt][nt], 0, 0, 0);
    __builtin_amdgcn_s_setprio(0);
  }

#pragma unroll
  for (int nt = 0; nt < 2; ++nt) {
    const int col = bn + wc * 32 + nt * 16 + (lane & 15);
    const float bv = bias[col];
#pragma unroll
    for (int mt = 0; mt < 4; ++mt) {
#pragma unroll
      for (int r = 0; r < 4; ++r) {
        const int row = bm + wr * 64 + mt * 16 + (lane >> 4) * 4 + r;
        const float v = acc[mt][nt][r] + bv;
        if (OUT_BF16) ((__bf16*)C)[(size_t)row * N + col] = (__bf16)v;
        else          ((float*)C)[(size_t)row * N + col]  = v;
      }
    }
  }
}

// ---------------- flash attention (Q = K = V), 32x32x16, z-split KV ----------------
// Round-7 proven body; z halves the KV range (grid 1024 -> 4 blk/CU at bounds(256,4)).
// Cross-half mx/lsum reductions: __shfl_xor (round-7 proven). P->PV A-frag exchange:
// v_permlane32_swap_b32 on DISTINCT values only (allocator cannot coalesce; lane map
// verified == round-7 ternary construction). Partial normalized O (bf16) + m,l (f32);
// k_merge combines halves.
#define SWZ2(row, col) ((row) * 64 + ((col) ^ (((((row) & 7) ^ ((row) >> 3)) & 7) << 3)))

__global__ __launch_bounds__(256, 4)
void k_attn(const __bf16* __restrict__ q, __bf16* __restrict__ op,
            float* __restrict__ ml) {
  __shared__ __align__(16) __bf16 Kt[64 * 64];
  __shared__ __align__(16) __bf16 Vt[64 * 64];
  const int tid = threadIdx.x, lane = tid & 63, w = tid >> 6;
  const int l31 = lane & 31, h = lane >> 5;
  const int bh = blockIdx.y, z = blockIdx.z;
  const size_t base = ((size_t)(bh >> 4) * 2048) * 1024 + (bh & 15) * 64;
  const int q0 = blockIdx.x * 128 + w * 32;
  const int kb = z * 1024;

  // Q B-frags: col q = q0+l31, k(d) = 16ks + 8h + 0..7
  bf16x8 qb[4];
#pragma unroll
  for (int ks = 0; ks < 4; ++ks)
    qb[ks] = *(const bf16x8*)&q[base + (size_t)(q0 + l31) * 1024 + ks * 16 + h * 8];

  f32x16 O[2] = {};                 // row q=(reg&3)+8*(reg>>2)+4h, col d=32dh+l31
  float m2 = -3e38f, l_run = 0.f;
  const float c2 = 0.18033688f;     // 0.125 * log2(e)

  const int r0 = tid >> 3, c0 = (tid & 7) * 8;   // staging coords

  const __bf16* gsrc = q + base + (size_t)(kb + r0) * 1024 + c0;
  // prologue: tile 0 of this half into registers
  bf16x8 v0 = *(const bf16x8*)&gsrc[0];
  bf16x8 v1 = *(const bf16x8*)&gsrc[32 * 1024];

  for (int t = 0; t < 16; ++t) {
    __syncthreads();                               // prior tile's LDS reads complete
    *(bf16x8*)&Kt[SWZ2(r0, c0)]      = v0;
    *(bf16x8*)&Kt[SWZ2(r0 + 32, c0)] = v1;
#pragma unroll
    for (int j = 0; j < 8; ++j) {
      Vt[SWZ2(c0 + j, r0)]      = v0[j];
      Vt[SWZ2(c0 + j, r0 + 32)] = v1[j];
    }
    __syncthreads();                               // tiles visible

    if (t < 15) {                                  // prefetch next tile
      v0 = *(const bf16x8*)&gsrc[(size_t)(t + 1) * 64 * 1024];
      v1 = *(const bf16x8*)&gsrc[(size_t)(t + 1) * 64 * 1024 + 32 * 1024];
    }

    // ---- QK^T: S^T[kv, q], 64kv x 32q per wave, 8 mfma
    f32x16 s[2] = {};
#pragma unroll
    for (int kvf = 0; kvf < 2; ++kvf) {
#pragma unroll
      for (int ks = 0; ks < 4; ++ks) {
        bf16x8 ka = *(const bf16x8*)&Kt[SWZ2(kvf * 32 + l31, ks * 16 + h * 8)];
        s[kvf] = __builtin_amdgcn_mfma_f32_32x32x16_bf16(ka, qb[ks], s[kvf], 0, 0, 0);
      }
    }

    // ---- online softmax (base-2, defer-rescale); lane's q = l31
    float tr[8];
#pragma unroll
    for (int r = 0; r < 8; ++r)
      tr[r] = fmaxf(fmaxf(s[0][r], s[0][r + 8]), fmaxf(s[1][r], s[1][r + 8]));
#pragma unroll
    for (int d = 4; d; d >>= 1)
#pragma unroll
      for (int r = 0; r < 4; ++r)
        if (r < d) tr[r] = fmaxf(tr[r], tr[r + d]);
    float mx = tr[0];
    mx = fmaxf(mx, __shfl_xor(mx, 32));            // cross-half max (proven path)
    mx *= c2;
    if (!__all(mx - m2 <= 5.77f)) {
      const float mnew = fmaxf(m2, mx);
      const float ps = exp2f(m2 - mnew);
      m2 = mnew;
      l_run *= ps;
#pragma unroll
      for (int r = 0; r < 16; ++r) {
        const int qrow = (r & 3) + 8 * (r >> 2) + 4 * h;
        const float rs = __shfl(ps, qrow);
        O[0][r] *= rs;
        O[1][r] *= rs;
      }
    }
    float ls0 = 0.f, ls1 = 0.f, ls2 = 0.f, ls3 = 0.f;
    unsigned P[2][4][2];
#pragma unroll
    for (int kvf = 0; kvf < 2; ++kvf) {
#pragma unroll
      for (int rq = 0; rq < 4; ++rq) {
#pragma unroll
        for (int tt = 0; tt < 2; ++tt) {
          const float p0 = exp2f(fmaf(s[kvf][rq * 4 + tt * 2],     c2, -m2));
          const float p1 = exp2f(fmaf(s[kvf][rq * 4 + tt * 2 + 1], c2, -m2));
          if (tt == 0) { ls0 += p0; ls1 += p1; } else { ls2 += p0; ls3 += p1; }
          union { __bf16 b[2]; unsigned u; } pk;
          pk.b[0] = (__bf16)p0; pk.b[1] = (__bf16)p1;
          P[kvf][rq][tt] = pk.u;
        }
      }
    }
    float lsum = (ls0 + ls1) + (ls2 + ls3);
    lsum += __shfl_xor(lsum, 32);                  // cross-half sum (proven path)
    l_run += lsum;

    // ---- PV A-frag words via permlane32_swap (operands always distinct values)
    unsigned pw[4][4];
#pragma unroll
    for (int ko = 0; ko < 4; ++ko) {
      const int kvf = ko >> 1, rqa = (ko & 1) * 2, rqb = rqa + 1;
      unsigned a0 = P[kvf][rqa][0], a1 = P[kvf][rqa][1];
      unsigned b0 = P[kvf][rqb][0], b1 = P[kvf][rqb][1];
      asm volatile("v_permlane32_swap_b32 %0, %1" : "+v"(a0), "+v"(b0));
      asm volatile("v_permlane32_swap_b32 %0, %1" : "+v"(a1), "+v"(b1));
      pw[ko][0] = a0; pw[ko][1] = a1; pw[ko][2] = b0; pw[ko][3] = b1;
    }

    // ---- PV: O[q,d] += P[q,kv] V[kv,d]
#pragma unroll
    for (int dh = 0; dh < 2; ++dh) {
#pragma unroll
      for (int ko = 0; ko < 4; ++ko) {
        union { unsigned u[4]; bf16x8 v; } pu;
        pu.u[0] = pw[ko][0]; pu.u[1] = pw[ko][1];
        pu.u[2] = pw[ko][2]; pu.u[3] = pw[ko][3];
        bf16x8 vb = *(const bf16x8*)&Vt[SWZ2(dh * 32 + l31, ko * 16 + h * 8)];
        O[dh] = __builtin_amdgcn_mfma_f32_32x32x16_bf16(pu.v, vb, O[dh], 0, 0, 0);
      }
    }
  }

  // ---- epilogue: normalized partial O (bf16) + m,l (f32)
  __bf16* opz = op + (size_t)z * 4194304;
  const float linv = 1.0f / l_run;
  if (h == 0) {
    const int mli = z * 65536 + bh * 2048 + (q0 + l31);
    ml[mli] = m2;
    ml[131072 + mli] = l_run;
  }
#pragma unroll
  for (int r = 0; r < 16; ++r) {
    const int qrow = (r & 3) + 8 * (r >> 2) + 4 * h;
    const float rs = __shfl(linv, qrow);
    opz[base + (size_t)(q0 + qrow) * 1024 + l31]      = (__bf16)(O[0][r] * rs);
    opz[base + (size_t)(q0 + qrow) * 1024 + 32 + l31] = (__bf16)(O[1][r] * rs);
  }
}

// ---------------- merge the two KV halves ----------------
__global__ __launch_bounds__(256)
void k_merge(const __bf16* __restrict__ op, const float* __restrict__ ml,
             __bf16* __restrict__ out) {
  const int idx = blockIdx.x * 256 + threadIdx.x;        // 524288 threads
  const int d8 = idx & 7, hh = (idx >> 3) & 15, row = idx >> 7;   // row 0..4095
  const int b = row >> 11, s = row & 2047;
  const int mli = (b * 16 + hh) * 2048 + s;
  const float mA = ml[mli],          mB = ml[65536 + mli];
  const float lA = ml[131072 + mli], lB = ml[196608 + mli];
  const float mS = fmaxf(mA, mB);
  const float wA = exp2f(mA - mS) * lA, wB = exp2f(mB - mS) * lB;
  const float inv = 1.0f / (wA + wB);
  const float fA = wA * inv, fB = wB * inv;
  const size_t off = (size_t)row * 1024 + hh * 64 + d8 * 8;
  bf16x8 a = *(const bf16x8*)&op[off];
  bf16x8 c = *(const bf16x8*)&op[4194304 + off];
  union { __bf16 h[8]; bf16x8 v; } r;
#pragma unroll
  for (int j = 0; j < 8; ++j)
    r.h[j] = (__bf16)((float)a[j] * fA + (float)c[j] * fB);
  *(bf16x8*)&out[off] = r.v;
}

// ---------------- launch ----------------
extern "C" void kernel_launch(void* const* d_in, const int* in_sizes, int n_in,
                              void* d_out, int out_size, void* d_ws, size_t ws_size,
                              hipStream_t stream) {
  const float* x  = (const float*)d_in[0];
  const float* Wq = (const float*)d_in[1];
  const float* bq = (const float*)d_in[2];
  const float* Wo = (const float*)d_in[3];
  const float* bo = (const float*)d_in[4];

  char* ws = (char*)d_ws;
  // Packing (37 MB high-water): ab aliases xb (xb dead after gemm1).
  __bf16* xb    = (__bf16*)(ws);                        // [0,8)   x bf16
  __bf16* ab    = (__bf16*)(ws);                        // [0,8)   merged attn out (aliases xb)
  __bf16* wqb   = (__bf16*)(ws + ((size_t)8  << 20));   // [8,10)
  __bf16* wob   = (__bf16*)(ws + ((size_t)10 << 20));   // [10,12)
  __bf16* qb    = (__bf16*)(ws + ((size_t)12 << 20));   // [12,20) q projection
  __bf16* opart = (__bf16*)(ws + ((size_t)20 << 20));   // [20,36) partial O (2 halves)
  float*  mlbuf = (float*) (ws + ((size_t)36 << 20));   // [36,37) m,l

  const int M = 4096, N = 1024, K = 1024;

  k_cvt<<<(M * K / 4 + 255) / 256, 256, 0, stream>>>(x,  xb,  M * K / 4);
  k_cvt<<<(N * K / 4 + 255) / 256, 256, 0, stream>>>(Wq, wqb, N * K / 4);
  k_cvt<<<(N * K / 4 + 255) / 256, 256, 0, stream>>>(Wo, wob, N * K / 4);

  k_gemm_bt<true ><<<dim3(16, 32), 256, 0, stream>>>(xb, wqb, bq, qb, M, N, K);
  k_attn          <<<dim3(16, 32, 2), 256, 0, stream>>>(qb, opart, mlbuf);
  k_merge         <<<2048, 256, 0, stream>>>(opart, mlbuf, ab);
  k_gemm_bt<false><<<dim3(16, 32), 256, 0, stream>>>(ab, wob, bo, d_out, M, N, K);
}

// Round 11
// 135.257 us; speedup vs baseline: 1.8571x; 1.8571x over previous
//
#include <hip/hip_runtime.h>
#include <hip/hip_bf16.h>

typedef __bf16 bf16x8 __attribute__((ext_vector_type(8)));
typedef float  f32x4  __attribute__((ext_vector_type(4)));
typedef float  f32x16 __attribute__((ext_vector_type(16)));

// async 16B global -> LDS (wave-uniform LDS base + lane*16)
__device__ __forceinline__ void gload_lds16(const void* g, void* l) {
  __builtin_amdgcn_global_load_lds(
      (const __attribute__((address_space(1))) unsigned int*)g,
      (__attribute__((address_space(3))) unsigned int*)l, 16, 0, 0);
}

// ---------------- fp32 -> bf16 convert (vectorized) ----------------
__global__ void k_cvt(const float* __restrict__ s, __bf16* __restrict__ d, int n4) {
  int i = blockIdx.x * blockDim.x + threadIdx.x;
  if (i >= n4) return;
  float4 v = ((const float4*)s)[i];
  union { __bf16 h[4]; uint2 u; } o;
  o.h[0] = (__bf16)v.x; o.h[1] = (__bf16)v.y;
  o.h[2] = (__bf16)v.z; o.h[3] = (__bf16)v.w;
  ((uint2*)d)[i] = o.u;
}

// ---------------- C[M,N] = A[M,K] @ B[N,K]^T + bias ---------------- (proven, verbatim)
template<bool OUT_BF16>
__global__ __launch_bounds__(256, 2)
void k_gemm_bt(const __bf16* __restrict__ A, const __bf16* __restrict__ B,
               const float* __restrict__ bias, void* __restrict__ C,
               int M, int N, int K) {
  __shared__ __align__(16) __bf16 At[128 * 32];
  __shared__ __align__(16) __bf16 Bt[64 * 32];
  const int tid  = threadIdx.x;
  const int lane = tid & 63;
  const int w    = tid >> 6;
  const int wr   = w >> 1, wc = w & 1;
  const int bm   = blockIdx.y * 128, bn = blockIdx.x * 64;

  f32x4 acc[4][2] = {};

  const __bf16* ga = A + (size_t)(bm + (tid >> 2)) * K + (tid & 3) * 8;
  const __bf16* gb = B + (size_t)(bn + (tid >> 2)) * K + (tid & 3) * 8;

  for (int k0 = 0; k0 < K; k0 += 32) {
    __syncthreads();
    gload_lds16(ga + k0,                  &At[(w * 16) * 32]);
    gload_lds16(ga + k0 + (size_t)64 * K, &At[(64 + w * 16) * 32]);
    gload_lds16(gb + k0,                  &Bt[(w * 16) * 32]);
    __syncthreads();

    bf16x8 a[4], b[2];
#pragma unroll
    for (int mt = 0; mt < 4; ++mt)
      a[mt] = *(const bf16x8*)&At[(wr * 64 + mt * 16 + (lane & 15)) * 32 + (lane >> 4) * 8];
#pragma unroll
    for (int nt = 0; nt < 2; ++nt)
      b[nt] = *(const bf16x8*)&Bt[(wc * 32 + nt * 16 + (lane & 15)) * 32 + (lane >> 4) * 8];
    __builtin_amdgcn_s_setprio(1);
#pragma unroll
    for (int mt = 0; mt < 4; ++mt)
#pragma unroll
      for (int nt = 0; nt < 2; ++nt)
        acc[mt][nt] = __builtin_amdgcn_mfma_f32_16x16x32_bf16(a[mt], b[nt], acc[mt][nt], 0, 0, 0);
    __builtin_amdgcn_s_setprio(0);
  }

#pragma unroll
  for (int nt = 0; nt < 2; ++nt) {
    const int col = bn + wc * 32 + nt * 16 + (lane & 15);
    const float bv = bias[col];
#pragma unroll
    for (int mt = 0; mt < 4; ++mt) {
#pragma unroll
      for (int r = 0; r < 4; ++r) {
        const int row = bm + wr * 64 + mt * 16 + (lane >> 4) * 4 + r;
        const float v = acc[mt][nt][r] + bv;
        if (OUT_BF16) ((__bf16*)C)[(size_t)row * N + col] = (__bf16)v;
        else          ((float*)C)[(size_t)row * N + col]  = v;
      }
    }
  }
}

// ---------------- flash attention (Q = K = V), 32x32x16, z-split KV ----------------
// Round-10 body (correctness proven), with launch_bounds back to (256,2): the (256,4)
// hint drove the allocator to a 64-VGPR budget -> spill -> 286 MB scratch traffic.
// At 84 VGPR (no spill) occupancy comes from the grid: 1024 blocks = 4 blk/CU.
#define SWZ2(row, col) ((row) * 64 + ((col) ^ (((((row) & 7) ^ ((row) >> 3)) & 7) << 3)))

__global__ __launch_bounds__(256, 2)
void k_attn(const __bf16* __restrict__ q, __bf16* __restrict__ op,
            float* __restrict__ ml) {
  __shared__ __align__(16) __bf16 Kt[64 * 64];
  __shared__ __align__(16) __bf16 Vt[64 * 64];
  const int tid = threadIdx.x, lane = tid & 63, w = tid >> 6;
  const int l31 = lane & 31, h = lane >> 5;
  const int bh = blockIdx.y, z = blockIdx.z;
  const size_t base = ((size_t)(bh >> 4) * 2048) * 1024 + (bh & 15) * 64;
  const int q0 = blockIdx.x * 128 + w * 32;
  const int kb = z * 1024;

  // Q B-frags: col q = q0+l31, k(d) = 16ks + 8h + 0..7
  bf16x8 qb[4];
#pragma unroll
  for (int ks = 0; ks < 4; ++ks)
    qb[ks] = *(const bf16x8*)&q[base + (size_t)(q0 + l31) * 1024 + ks * 16 + h * 8];

  f32x16 O[2] = {};                 // row q=(reg&3)+8*(reg>>2)+4h, col d=32dh+l31
  float m2 = -3e38f, l_run = 0.f;
  const float c2 = 0.18033688f;     // 0.125 * log2(e)

  const int r0 = tid >> 3, c0 = (tid & 7) * 8;   // staging coords

  const __bf16* gsrc = q + base + (size_t)(kb + r0) * 1024 + c0;
  // prologue: tile 0 of this half into registers
  bf16x8 v0 = *(const bf16x8*)&gsrc[0];
  bf16x8 v1 = *(const bf16x8*)&gsrc[32 * 1024];

  for (int t = 0; t < 16; ++t) {
    __syncthreads();                               // prior tile's LDS reads complete
    *(bf16x8*)&Kt[SWZ2(r0, c0)]      = v0;
    *(bf16x8*)&Kt[SWZ2(r0 + 32, c0)] = v1;
#pragma unroll
    for (int j = 0; j < 8; ++j) {
      Vt[SWZ2(c0 + j, r0)]      = v0[j];
      Vt[SWZ2(c0 + j, r0 + 32)] = v1[j];
    }
    __syncthreads();                               // tiles visible

    if (t < 15) {                                  // prefetch next tile
      v0 = *(const bf16x8*)&gsrc[(size_t)(t + 1) * 64 * 1024];
      v1 = *(const bf16x8*)&gsrc[(size_t)(t + 1) * 64 * 1024 + 32 * 1024];
    }

    // ---- QK^T: S^T[kv, q], 64kv x 32q per wave, 8 mfma
    f32x16 s[2] = {};
#pragma unroll
    for (int kvf = 0; kvf < 2; ++kvf) {
#pragma unroll
      for (int ks = 0; ks < 4; ++ks) {
        bf16x8 ka = *(const bf16x8*)&Kt[SWZ2(kvf * 32 + l31, ks * 16 + h * 8)];
        s[kvf] = __builtin_amdgcn_mfma_f32_32x32x16_bf16(ka, qb[ks], s[kvf], 0, 0, 0);
      }
    }

    // ---- online softmax (base-2, defer-rescale); lane's q = l31
    float tr[8];
#pragma unroll
    for (int r = 0; r < 8; ++r)
      tr[r] = fmaxf(fmaxf(s[0][r], s[0][r + 8]), fmaxf(s[1][r], s[1][r + 8]));
#pragma unroll
    for (int d = 4; d; d >>= 1)
#pragma unroll
      for (int r = 0; r < 4; ++r)
        if (r < d) tr[r] = fmaxf(tr[r], tr[r + d]);
    float mx = tr[0];
    mx = fmaxf(mx, __shfl_xor(mx, 32));            // cross-half max (proven path)
    mx *= c2;
    if (!__all(mx - m2 <= 5.77f)) {
      const float mnew = fmaxf(m2, mx);
      const float ps = exp2f(m2 - mnew);
      m2 = mnew;
      l_run *= ps;
#pragma unroll
      for (int r = 0; r < 16; ++r) {
        const int qrow = (r & 3) + 8 * (r >> 2) + 4 * h;
        const float rs = __shfl(ps, qrow);
        O[0][r] *= rs;
        O[1][r] *= rs;
      }
    }
    float ls0 = 0.f, ls1 = 0.f, ls2 = 0.f, ls3 = 0.f;
    unsigned P[2][4][2];
#pragma unroll
    for (int kvf = 0; kvf < 2; ++kvf) {
#pragma unroll
      for (int rq = 0; rq < 4; ++rq) {
#pragma unroll
        for (int tt = 0; tt < 2; ++tt) {
          const float p0 = exp2f(fmaf(s[kvf][rq * 4 + tt * 2],     c2, -m2));
          const float p1 = exp2f(fmaf(s[kvf][rq * 4 + tt * 2 + 1], c2, -m2));
          if (tt == 0) { ls0 += p0; ls1 += p1; } else { ls2 += p0; ls3 += p1; }
          union { __bf16 b[2]; unsigned u; } pk;
          pk.b[0] = (__bf16)p0; pk.b[1] = (__bf16)p1;
          P[kvf][rq][tt] = pk.u;
        }
      }
    }
    float lsum = (ls0 + ls1) + (ls2 + ls3);
    lsum += __shfl_xor(lsum, 32);                  // cross-half sum (proven path)
    l_run += lsum;

    // ---- PV A-frag words via permlane32_swap (operands always distinct values)
    unsigned pw[4][4];
#pragma unroll
    for (int ko = 0; ko < 4; ++ko) {
      const int kvf = ko >> 1, rqa = (ko & 1) * 2, rqb = rqa + 1;
      unsigned a0 = P[kvf][rqa][0], a1 = P[kvf][rqa][1];
      unsigned b0 = P[kvf][rqb][0], b1 = P[kvf][rqb][1];
      asm volatile("v_permlane32_swap_b32 %0, %1" : "+v"(a0), "+v"(b0));
      asm volatile("v_permlane32_swap_b32 %0, %1" : "+v"(a1), "+v"(b1));
      pw[ko][0] = a0; pw[ko][1] = a1; pw[ko][2] = b0; pw[ko][3] = b1;
    }

    // ---- PV: O[q,d] += P[q,kv] V[kv,d]
#pragma unroll
    for (int dh = 0; dh < 2; ++dh) {
#pragma unroll
      for (int ko = 0; ko < 4; ++ko) {
        union { unsigned u[4]; bf16x8 v; } pu;
        pu.u[0] = pw[ko][0]; pu.u[1] = pw[ko][1];
        pu.u[2] = pw[ko][2]; pu.u[3] = pw[ko][3];
        bf16x8 vb = *(const bf16x8*)&Vt[SWZ2(dh * 32 + l31, ko * 16 + h * 8)];
        O[dh] = __builtin_amdgcn_mfma_f32_32x32x16_bf16(pu.v, vb, O[dh], 0, 0, 0);
      }
    }
  }

  // ---- epilogue: normalized partial O (bf16) + m,l (f32)
  __bf16* opz = op + (size_t)z * 4194304;
  const float linv = 1.0f / l_run;
  if (h == 0) {
    const int mli = z * 65536 + bh * 2048 + (q0 + l31);
    ml[mli] = m2;
    ml[131072 + mli] = l_run;
  }
#pragma unroll
  for (int r = 0; r < 16; ++r) {
    const int qrow = (r & 3) + 8 * (r >> 2) + 4 * h;
    const float rs = __shfl(linv, qrow);
    opz[base + (size_t)(q0 + qrow) * 1024 + l31]      = (__bf16)(O[0][r] * rs);
    opz[base + (size_t)(q0 + qrow) * 1024 + 32 + l31] = (__bf16)(O[1][r] * rs);
  }
}

// ---------------- merge the two KV halves ----------------
__global__ __launch_bounds__(256)
void k_merge(const __bf16* __restrict__ op, const float* __restrict__ ml,
             __bf16* __restrict__ out) {
  const int idx = blockIdx.x * 256 + threadIdx.x;        // 524288 threads
  const int d8 = idx & 7, hh = (idx >> 3) & 15, row = idx >> 7;   // row 0..4095
  const int b = row >> 11, s = row & 2047;
  const int mli = (b * 16 + hh) * 2048 + s;
  const float mA = ml[mli],          mB = ml[65536 + mli];
  const float lA = ml[131072 + mli], lB = ml[196608 + mli];
  const float mS = fmaxf(mA, mB);
  const float wA = exp2f(mA - mS) * lA, wB = exp2f(mB - mS) * lB;
  const float inv = 1.0f / (wA + wB);
  const float fA = wA * inv, fB = wB * inv;
  const size_t off = (size_t)row * 1024 + hh * 64 + d8 * 8;
  bf16x8 a = *(const bf16x8*)&op[off];
  bf16x8 c = *(const bf16x8*)&op[4194304 + off];
  union { __bf16 h[8]; bf16x8 v; } r;
#pragma unroll
  for (int j = 0; j < 8; ++j)
    r.h[j] = (__bf16)((float)a[j] * fA + (float)c[j] * fB);
  *(bf16x8*)&out[off] = r.v;
}

// ---------------- launch ----------------
extern "C" void kernel_launch(void* const* d_in, const int* in_sizes, int n_in,
                              void* d_out, int out_size, void* d_ws, size_t ws_size,
                              hipStream_t stream) {
  const float* x  = (const float*)d_in[0];
  const float* Wq = (const float*)d_in[1];
  const float* bq = (const float*)d_in[2];
  const float* Wo = (const float*)d_in[3];
  const float* bo = (const float*)d_in[4];

  char* ws = (char*)d_ws;
  // Packing (37 MB high-water): ab aliases xb (xb dead after gemm1).
  __bf16* xb    = (__bf16*)(ws);                        // [0,8)   x bf16
  __bf16* ab    = (__bf16*)(ws);                        // [0,8)   merged attn out (aliases xb)
  __bf16* wqb   = (__bf16*)(ws + ((size_t)8  << 20));   // [8,10)
  __bf16* wob   = (__bf16*)(ws + ((size_t)10 << 20));   // [10,12)
  __bf16* qb    = (__bf16*)(ws + ((size_t)12 << 20));   // [12,20) q projection
  __bf16* opart = (__bf16*)(ws + ((size_t)20 << 20));   // [20,36) partial O (2 halves)
  float*  mlbuf = (float*) (ws + ((size_t)36 << 20));   // [36,37) m,l

  const int M = 4096, N = 1024, K = 1024;

  k_cvt<<<(M * K / 4 + 255) / 256, 256, 0, stream>>>(x,  xb,  M * K / 4);
  k_cvt<<<(N * K / 4 + 255) / 256, 256, 0, stream>>>(Wq, wqb, N * K / 4);
  k_cvt<<<(N * K / 4 + 255) / 256, 256, 0, stream>>>(Wo, wob, N * K / 4);

  k_gemm_bt<true ><<<dim3(16, 32), 256, 0, stream>>>(xb, wqb, bq, qb, M, N, K);
  k_attn          <<<dim3(16, 32, 2), 256, 0, stream>>>(qb, opart, mlbuf);
  k_merge         <<<2048, 256, 0, stream>>>(opart, mlbuf, ab);
  k_gemm_bt<false><<<dim3(16, 32), 256, 0, stream>>>(ab, wob, bo, d_out, M, N, K);
}

// Round 12
// 128.930 us; speedup vs baseline: 1.9482x; 1.0491x over previous
//
#include <hip/hip_runtime.h>
#include <hip/hip_bf16.h>

typedef __bf16 bf16x8 __attribute__((ext_vector_type(8)));
typedef float  f32x4  __attribute__((ext_vector_type(4)));
typedef float  f32x16 __attribute__((ext_vector_type(16)));

// async 16B global -> LDS (wave-uniform LDS base + lane*16)
__device__ __forceinline__ void gload_lds16(const void* g, void* l) {
  __builtin_amdgcn_global_load_lds(
      (const __attribute__((address_space(1))) unsigned int*)g,
      (__attribute__((address_space(3))) unsigned int*)l, 16, 0, 0);
}

// ---------------- fp32 -> bf16 convert (vectorized) ----------------
__global__ void k_cvt(const float* __restrict__ s, __bf16* __restrict__ d, int n4) {
  int i = blockIdx.x * blockDim.x + threadIdx.x;
  if (i >= n4) return;
  float4 v = ((const float4*)s)[i];
  union { __bf16 h[4]; uint2 u; } o;
  o.h[0] = (__bf16)v.x; o.h[1] = (__bf16)v.y;
  o.h[2] = (__bf16)v.z; o.h[3] = (__bf16)v.w;
  ((uint2*)d)[i] = o.u;
}

// ---------------- C[M,N] = A[M,K] @ B[N,K]^T + bias ---------------- (proven, verbatim)
template<bool OUT_BF16>
__global__ __launch_bounds__(256, 2)
void k_gemm_bt(const __bf16* __restrict__ A, const __bf16* __restrict__ B,
               const float* __restrict__ bias, void* __restrict__ C,
               int M, int N, int K) {
  __shared__ __align__(16) __bf16 At[128 * 32];
  __shared__ __align__(16) __bf16 Bt[64 * 32];
  const int tid  = threadIdx.x;
  const int lane = tid & 63;
  const int w    = tid >> 6;
  const int wr   = w >> 1, wc = w & 1;
  const int bm   = blockIdx.y * 128, bn = blockIdx.x * 64;

  f32x4 acc[4][2] = {};

  const __bf16* ga = A + (size_t)(bm + (tid >> 2)) * K + (tid & 3) * 8;
  const __bf16* gb = B + (size_t)(bn + (tid >> 2)) * K + (tid & 3) * 8;

  for (int k0 = 0; k0 < K; k0 += 32) {
    __syncthreads();
    gload_lds16(ga + k0,                  &At[(w * 16) * 32]);
    gload_lds16(ga + k0 + (size_t)64 * K, &At[(64 + w * 16) * 32]);
    gload_lds16(gb + k0,                  &Bt[(w * 16) * 32]);
    __syncthreads();

    bf16x8 a[4], b[2];
#pragma unroll
    for (int mt = 0; mt < 4; ++mt)
      a[mt] = *(const bf16x8*)&At[(wr * 64 + mt * 16 + (lane & 15)) * 32 + (lane >> 4) * 8];
#pragma unroll
    for (int nt = 0; nt < 2; ++nt)
      b[nt] = *(const bf16x8*)&Bt[(wc * 32 + nt * 16 + (lane & 15)) * 32 + (lane >> 4) * 8];
    __builtin_amdgcn_s_setprio(1);
#pragma unroll
    for (int mt = 0; mt < 4; ++mt)
#pragma unroll
      for (int nt = 0; nt < 2; ++nt)
        acc[mt][nt] = __builtin_amdgcn_mfma_f32_16x16x32_bf16(a[mt], b[nt], acc[mt][nt], 0, 0, 0);
    __builtin_amdgcn_s_setprio(0);
  }

#pragma unroll
  for (int nt = 0; nt < 2; ++nt) {
    const int col = bn + wc * 32 + nt * 16 + (lane & 15);
    const float bv = bias[col];
#pragma unroll
    for (int mt = 0; mt < 4; ++mt) {
#pragma unroll
      for (int r = 0; r < 4; ++r) {
        const int row = bm + wr * 64 + mt * 16 + (lane >> 4) * 4 + r;
        const float v = acc[mt][nt][r] + bv;
        if (OUT_BF16) ((__bf16*)C)[(size_t)row * N + col] = (__bf16)v;
        else          ((float*)C)[(size_t)row * N + col]  = v;
      }
    }
  }
}

// ---------------- flash attention (Q = K = V), 32x32x16 MFMA ----------------
// Round-11-proven body, z-split removed (grid (16,32), 32 tiles, direct output).
// VALU cuts: (a) adjacent-row staging -> Vt transpose as 8 packed b32 writes
// (bank-checked 2-way = free; was 16 scalar b16), (b) in-place permlane swap on P
// (no pw copy), (c) s_setprio around MFMA clusters.
#define SWZ2(row, col) ((row) * 64 + ((col) ^ (((((row) & 7) ^ ((row) >> 3)) & 7) << 3)))

__global__ __launch_bounds__(256, 2)
void k_attn(const __bf16* __restrict__ q, __bf16* __restrict__ o) {
  __shared__ __align__(16) __bf16 Kt[64 * 64];
  __shared__ __align__(16) __bf16 Vt[64 * 64];
  const int tid = threadIdx.x, lane = tid & 63, w = tid >> 6;
  const int l31 = lane & 31, h = lane >> 5;
  const int bh = blockIdx.y;
  const size_t base = ((size_t)(bh >> 4) * 2048) * 1024 + (bh & 15) * 64;
  const int q0 = blockIdx.x * 128 + w * 32;

  // Q B-frags: col q = q0+l31, k(d) = 16ks + 8h + 0..7
  bf16x8 qb[4];
#pragma unroll
  for (int ks = 0; ks < 4; ++ks)
    qb[ks] = *(const bf16x8*)&q[base + (size_t)(q0 + l31) * 1024 + ks * 16 + h * 8];

  f32x16 O[2] = {};                 // row q=(reg&3)+8*(reg>>2)+4h, col d=32dh+l31
  float m2 = -3e38f, l_run = 0.f;
  const float c2 = 0.18033688f;     // 0.125 * log2(e)

  // staging: thread covers kv rows 2sm, 2sm+1, cols c0..c0+7 (adjacent rows ->
  // packed b32 Vt transpose writes)
  const int sm = tid >> 3, c0 = (tid & 7) * 8;
  const __bf16* gsrc = q + base + (size_t)(2 * sm) * 1024 + c0;

  // prologue: tile 0 into registers
  bf16x8 v0 = *(const bf16x8*)&gsrc[0];
  bf16x8 v1 = *(const bf16x8*)&gsrc[1024];

  for (int t = 0; t < 32; ++t) {
    __syncthreads();                               // prior tile's LDS reads complete
    *(bf16x8*)&Kt[SWZ2(2 * sm, c0)]     = v0;
    *(bf16x8*)&Kt[SWZ2(2 * sm + 1, c0)] = v1;
#pragma unroll
    for (int j = 0; j < 8; ++j) {
      union { __bf16 b[2]; unsigned u; } pk;
      pk.b[0] = v0[j]; pk.b[1] = v1[j];
      *(unsigned*)&Vt[SWZ2(c0 + j, 2 * sm)] = pk.u;
    }
    __syncthreads();                               // tile visible

    if (t < 31) {                                  // prefetch next tile
      v0 = *(const bf16x8*)&gsrc[(size_t)(t + 1) * 64 * 1024];
      v1 = *(const bf16x8*)&gsrc[(size_t)(t + 1) * 64 * 1024 + 1024];
    }

    // ---- QK^T: S^T[kv, q], 64kv x 32q per wave, 8 mfma
    f32x16 s[2] = {};
#pragma unroll
    for (int kvf = 0; kvf < 2; ++kvf) {
      __builtin_amdgcn_s_setprio(1);
#pragma unroll
      for (int ks = 0; ks < 4; ++ks) {
        bf16x8 ka = *(const bf16x8*)&Kt[SWZ2(kvf * 32 + l31, ks * 16 + h * 8)];
        s[kvf] = __builtin_amdgcn_mfma_f32_32x32x16_bf16(ka, qb[ks], s[kvf], 0, 0, 0);
      }
      __builtin_amdgcn_s_setprio(0);
    }

    // ---- online softmax (base-2, defer-rescale); lane's q = l31
    float tr[8];
#pragma unroll
    for (int r = 0; r < 8; ++r)
      tr[r] = fmaxf(fmaxf(s[0][r], s[0][r + 8]), fmaxf(s[1][r], s[1][r + 8]));
#pragma unroll
    for (int d = 4; d; d >>= 1)
#pragma unroll
      for (int r = 0; r < 4; ++r)
        if (r < d) tr[r] = fmaxf(tr[r], tr[r + d]);
    float mx = tr[0];
    mx = fmaxf(mx, __shfl_xor(mx, 32));            // cross-half max
    mx *= c2;
    if (!__all(mx - m2 <= 5.77f)) {
      const float mnew = fmaxf(m2, mx);
      const float ps = exp2f(m2 - mnew);
      m2 = mnew;
      l_run *= ps;
#pragma unroll
      for (int r = 0; r < 16; ++r) {
        const int qrow = (r & 3) + 8 * (r >> 2) + 4 * h;
        const float rs = __shfl(ps, qrow);
        O[0][r] *= rs;
        O[1][r] *= rs;
      }
    }
    float ls0 = 0.f, ls1 = 0.f, ls2 = 0.f, ls3 = 0.f;
    unsigned P[2][4][2];
#pragma unroll
    for (int kvf = 0; kvf < 2; ++kvf) {
#pragma unroll
      for (int rq = 0; rq < 4; ++rq) {
#pragma unroll
        for (int tt = 0; tt < 2; ++tt) {
          const float p0 = exp2f(fmaf(s[kvf][rq * 4 + tt * 2],     c2, -m2));
          const float p1 = exp2f(fmaf(s[kvf][rq * 4 + tt * 2 + 1], c2, -m2));
          if (tt == 0) { ls0 += p0; ls1 += p1; } else { ls2 += p0; ls3 += p1; }
          union { __bf16 b[2]; unsigned u; } pk;
          pk.b[0] = (__bf16)p0; pk.b[1] = (__bf16)p1;
          P[kvf][rq][tt] = pk.u;
        }
      }
    }
    float lsum = (ls0 + ls1) + (ls2 + ls3);
    lsum += __shfl_xor(lsum, 32);                  // cross-half sum
    l_run += lsum;

    // ---- in-place permlane swap: after this, P[kvf][{rqa,rqb}][*] hold the
    // PV A-frag words for both dh passes (operands distinct -> no coalescing)
#pragma unroll
    for (int ko = 0; ko < 4; ++ko) {
      const int kvf = ko >> 1, rqa = (ko & 1) * 2, rqb = rqa + 1;
      asm volatile("v_permlane32_swap_b32 %0, %1"
                   : "+v"(P[kvf][rqa][0]), "+v"(P[kvf][rqb][0]));
      asm volatile("v_permlane32_swap_b32 %0, %1"
                   : "+v"(P[kvf][rqa][1]), "+v"(P[kvf][rqb][1]));
    }

    // ---- PV: O[q,d] += P[q,kv] V[kv,d]
#pragma unroll
    for (int dh = 0; dh < 2; ++dh) {
      __builtin_amdgcn_s_setprio(1);
#pragma unroll
      for (int ko = 0; ko < 4; ++ko) {
        const int kvf = ko >> 1, rqa = (ko & 1) * 2, rqb = rqa + 1;
        union { unsigned u[4]; bf16x8 v; } pu;
        pu.u[0] = P[kvf][rqa][0]; pu.u[1] = P[kvf][rqa][1];
        pu.u[2] = P[kvf][rqb][0]; pu.u[3] = P[kvf][rqb][1];
        bf16x8 vb = *(const bf16x8*)&Vt[SWZ2(dh * 32 + l31, ko * 16 + h * 8)];
        O[dh] = __builtin_amdgcn_mfma_f32_32x32x16_bf16(pu.v, vb, O[dh], 0, 0, 0);
      }
      __builtin_amdgcn_s_setprio(0);
    }
  }

  // ---- epilogue: O / l, store bf16
  const float linv = 1.0f / l_run;
#pragma unroll
  for (int r = 0; r < 16; ++r) {
    const int qrow = (r & 3) + 8 * (r >> 2) + 4 * h;
    const float rs = __shfl(linv, qrow);
    o[base + (size_t)(q0 + qrow) * 1024 + l31]      = (__bf16)(O[0][r] * rs);
    o[base + (size_t)(q0 + qrow) * 1024 + 32 + l31] = (__bf16)(O[1][r] * rs);
  }
}

// ---------------- launch ----------------
extern "C" void kernel_launch(void* const* d_in, const int* in_sizes, int n_in,
                              void* d_out, int out_size, void* d_ws, size_t ws_size,
                              hipStream_t stream) {
  const float* x  = (const float*)d_in[0];
  const float* Wq = (const float*)d_in[1];
  const float* bq = (const float*)d_in[2];
  const float* Wo = (const float*)d_in[3];
  const float* bo = (const float*)d_in[4];

  char* ws = (char*)d_ws;
  __bf16* xb  = (__bf16*)(ws);                          // [0,8)   x bf16
  __bf16* ab  = (__bf16*)(ws);                          // [0,8)   attn out (aliases xb; xb dead)
  __bf16* wqb = (__bf16*)(ws + ((size_t)8  << 20));     // [8,10)
  __bf16* wob = (__bf16*)(ws + ((size_t)10 << 20));     // [10,12)
  __bf16* qb  = (__bf16*)(ws + ((size_t)12 << 20));     // [12,20) q projection

  const int M = 4096, N = 1024, K = 1024;

  k_cvt<<<(M * K / 4 + 255) / 256, 256, 0, stream>>>(x,  xb,  M * K / 4);
  k_cvt<<<(N * K / 4 + 255) / 256, 256, 0, stream>>>(Wq, wqb, N * K / 4);
  k_cvt<<<(N * K / 4 + 255) / 256, 256, 0, stream>>>(Wo, wob, N * K / 4);

  k_gemm_bt<true ><<<dim3(16, 32), 256, 0, stream>>>(xb, wqb, bq, qb, M, N, K);
  k_attn          <<<dim3(16, 32), 256, 0, stream>>>(qb, ab);
  k_gemm_bt<false><<<dim3(16, 32), 256, 0, stream>>>(ab, wob, bo, d_out, M, N, K);
}